// Round 17
// baseline (3111.406 us; speedup 1.0000x reference)
//
#include <hip/hip_runtime.h>
#include <hip/hip_bf16.h>
#include <stdint.h>

// Problem constants
#define KVOL   27
#define MPAIRS 150000
#define NROWS  200000            // N_IN == N_OUT
#define CDIM   64
#define TOTALC (KVOL*MPAIRS)     // 4,050,000

// Pass / bucket geometry
#define NPASS  3
#define KPP    9                 // k-offsets per pass
#define PASSC  (KPP*MPAIRS)      // 1,350,000
#define BROWS  128
#define NBKT   1563              // ceil(200000/128)
#define NPB    (NPASS*NBKT)      // 4689 (pass,bucket) bins
#define SUBW   8                 // sub-chunks per k for hist/scatter (divides 150000)
#define NWGH   (KVOL*SUBW)       // 216 WGs
#define CHUNKH (MPAIRS/SUBW)     // 18,750 exact
#define CELLS  (NPB*NWGH)        // 1,012,824 scan cells (sb=990 < 1024)
#define ECAP   1280              // per-(pass,bucket) entry capacity (mean 864, sd 29)

typedef __attribute__((ext_vector_type(8))) short bf16x8;
typedef __attribute__((ext_vector_type(4))) float f32x4;

__device__ __forceinline__ unsigned short f2bfu(float f) {
  union { float f; uint32_t u; } v; v.f = f;
  uint32_t u = v.u;
  u += 0x7FFF + ((u >> 16) & 1);
  return (unsigned short)(u >> 16);
}
__device__ __forceinline__ short f2bf(float f) { return (short)f2bfu(f); }
__device__ __forceinline__ float bf2f(uint32_t u16) {
  union { uint32_t u; float f; } v; v.u = u16 << 16; return v.f;
}

// ---- prologue: fused feats + weights convert (one launch) ----
__global__ void cvt_all(const float* __restrict__ in, short* __restrict__ out,
                        const float* __restrict__ w, short* __restrict__ wt, int n8) {
  if (blockIdx.x < KVOL) {                     // weight transpose blocks
    int k = blockIdx.x;
    const float* wk = w + (size_t)k * CDIM * CDIM;
    short* wtk = wt + (size_t)k * CDIM * CDIM;
    for (int t = threadIdx.x; t < CDIM * CDIM; t += blockDim.x) {
      int j = t >> 6, i = t & 63;
      wtk[j * CDIM + i] = f2bf(wk[i * CDIM + j]);
    }
    return;
  }
  int i = (blockIdx.x - KVOL) * blockDim.x + threadIdx.x;
  int stride = (gridDim.x - KVOL) * blockDim.x;
  for (; i < n8; i += stride) {
    const float* p = in + (size_t)i * 8;
    f32x4 f0 = *(const f32x4*)(p);
    f32x4 f1 = *(const f32x4*)(p + 4);
    bf16x8 o;
    o[0] = f2bf(f0[0]); o[1] = f2bf(f0[1]); o[2] = f2bf(f0[2]); o[3] = f2bf(f0[3]);
    o[4] = f2bf(f1[0]); o[5] = f2bf(f1[1]); o[6] = f2bf(f1[2]); o[7] = f2bf(f1[3]);
    *(bf16x8*)(out + (size_t)i * 8) = o;
  }
}

// ---- histogram: WG = (k, sub-chunk); LDS-private 1563 bucket bins ----
__global__ __launch_bounds__(256)
void k_hist(const int* __restrict__ om, unsigned int* __restrict__ hist_g) {
  __shared__ unsigned int h[NBKT];
  const int wg = blockIdx.x, tid = threadIdx.x;
  const int k = wg / SUBW, sub = wg - k * SUBW;
  const int pass = k / KPP;
  for (int i = tid; i < NBKT; i += 256) h[i] = 0u;
  __syncthreads();
  const int base = k * MPAIRS + sub * CHUNKH;
  for (int i = tid; i < CHUNKH; i += 256)
    atomicAdd(&h[((unsigned)om[base + i]) >> 7], 1u);
  __syncthreads();
  for (int b = tid; b < NBKT; b += 256)
    hist_g[(size_t)(pass * NBKT + b) * NWGH + wg] = h[b];
}

// ---- 3-kernel exclusive scan over CELLS ([bin][wg] cell-major) ----
__global__ void scan_local(const unsigned int* __restrict__ counts,
                           unsigned int* __restrict__ offsets,
                           unsigned int* __restrict__ bsum, int n) {
  __shared__ unsigned int sh[1024];
  int t = threadIdx.x;
  int idx = blockIdx.x * 1024 + t;
  unsigned int v = (idx < n) ? counts[idx] : 0u;
  sh[t] = v; __syncthreads();
  for (int o = 1; o < 1024; o <<= 1) {
    unsigned int u = (t >= o) ? sh[t - o] : 0u;
    __syncthreads();
    sh[t] += u;
    __syncthreads();
  }
  if (idx < n) offsets[idx] = sh[t] - v;
  if (t == 1023) bsum[blockIdx.x] = sh[1023];
}

__global__ void scan_bsum(unsigned int* __restrict__ bsum, int nb) {
  __shared__ unsigned int sh[1024];
  int t = threadIdx.x;
  unsigned int v = (t < nb) ? bsum[t] : 0u;
  sh[t] = v; __syncthreads();
  for (int o = 1; o < 1024; o <<= 1) {
    unsigned int u = (t >= o) ? sh[t - o] : 0u;
    __syncthreads();
    sh[t] += u;
    __syncthreads();
  }
  if (t < nb) bsum[t] = sh[t] - v;
}

__global__ void scan_apply(unsigned int* __restrict__ offsets,
                           const unsigned int* __restrict__ bsum,
                           const unsigned int* __restrict__ counts, int n) {
  int idx = blockIdx.x * 1024 + threadIdx.x;
  if (idx < n) {
    unsigned int o = offsets[idx] + bsum[blockIdx.x];
    offsets[idx] = o;
    if (idx == n - 1) offsets[n] = o + counts[idx];
  }
}

// ---- scatter: entry (outl<<21|e_local) into (pass,bucket) slot; ALSO emits
// the inverse permutation inv[e] = slot (coalesced write). ----
__global__ __launch_bounds__(256)
void k_scatter(const int* __restrict__ om,
               const unsigned int* __restrict__ offs,
               unsigned int* __restrict__ sorted_g,
               unsigned int* __restrict__ inv) {
  __shared__ unsigned int cur[NBKT];
  const int wg = blockIdx.x, tid = threadIdx.x;
  const int k = wg / SUBW, sub = wg - k * SUBW;
  const int pass = k / KPP, kk = k - pass * KPP;
  for (int b = tid; b < NBKT; b += 256)
    cur[b] = offs[(size_t)(pass * NBKT + b) * NWGH + wg];
  __syncthreads();
  const int base = k * MPAIRS + sub * CHUNKH;
  const unsigned int elb = (unsigned)(kk * MPAIRS + sub * CHUNKH);
  for (int i = tid; i < CHUNKH; i += 256) {
    unsigned int o = (unsigned)om[base + i];
    unsigned int pos = atomicAdd(&cur[o >> 7], 1u);
    sorted_g[pos] = ((o & 127u) << 21) | (elb + (unsigned)i);
    inv[base + i] = pos;                       // coalesced
  }
}

// ---- GEMM (per pass): k-major loop (coalesced in_map/inv reads), writes
// channel-transposed SLOT-ORDERED contrib: 32 u32 planes [cl][slot].
// Plane chunk per store = full 64B lines. Zero atomics. ----
__global__ __launch_bounds__(256, 8)
void k_gemm(const short* __restrict__ a_bf16, const short* __restrict__ wt_bf16,
            const int* __restrict__ in_map, const unsigned int* __restrict__ inv,
            unsigned int* __restrict__ contrib, int pass)
{
  const int kk   = blockIdx.y;
  const int k    = pass * KPP + kk;
  const int lane = threadIdx.x & 63;
  const int wave = threadIdx.x >> 6;
  const int r    = lane & 15;
  const int h    = lane >> 4;

  bf16x8 b[4][2];
  const short* wtk = wt_bf16 + (size_t)k * CDIM * CDIM;
#pragma unroll
  for (int t = 0; t < 4; ++t)
#pragma unroll
    for (int c = 0; c < 2; ++c)
      b[t][c] = *(const bf16x8*)(wtk + (t * 16 + r) * CDIM + c * 32 + h * 8);

  const int* imk = in_map + (size_t)k * MPAIRS;
  const unsigned int* invk = inv + (size_t)k * MPAIRS;
  const unsigned int pbase = (unsigned int)pass * (unsigned int)PASSC;
  const int ntiles = MPAIRS / 16;
  const int wstride = gridDim.x * 4;

  for (int tile = blockIdx.x * 4 + wave; tile < ntiles; tile += wstride) {
    const int base = tile * 16;
    const int in_row = imk[base + r];
    const unsigned int ci = invk[base + r] - pbase;    // slot within pass
    const short* arow = a_bf16 + (size_t)in_row * CDIM;
    bf16x8 a0 = *(const bf16x8*)(arow + h * 8);
    bf16x8 a1 = *(const bf16x8*)(arow + 32 + h * 8);

    f32x4 acc[4];
#pragma unroll
    for (int t = 0; t < 4; ++t) {
      acc[t] = (f32x4){0.f, 0.f, 0.f, 0.f};
      acc[t] = __builtin_amdgcn_mfma_f32_16x16x32_bf16(b[t][0], a0, acc[t], 0, 0, 0);
      acc[t] = __builtin_amdgcn_mfma_f32_16x16x32_bf16(b[t][1], a1, acc[t], 0, 0, 0);
    }

    // planes t*8+h*2 and +1 hold channels (t*16+h*4 + {0,1}) and ({2,3})
#pragma unroll
    for (int t = 0; t < 4; ++t) {
      uint32_t lo = (uint32_t)f2bfu(acc[t][0]) | ((uint32_t)f2bfu(acc[t][1]) << 16);
      uint32_t hi = (uint32_t)f2bfu(acc[t][2]) | ((uint32_t)f2bfu(acc[t][3]) << 16);
      contrib[(size_t)(t * 8 + h * 2) * PASSC + ci] = lo;
      contrib[(size_t)(t * 8 + h * 2 + 1) * PASSC + ci] = hi;
    }
  }
}

// ---- reduce (per pass): WG(512) per bucket; in-LDS row-sort stores the
// segment-relative slot index; per-row reads hit the bucket's ~110KB
// contrib window (plane-major: 16 entries per 64B line -> L2-local). ----
__global__ __launch_bounds__(512, 4)
void k_reduce(const unsigned int* __restrict__ contrib,
              const unsigned int* __restrict__ sorted_g,
              const unsigned int* __restrict__ offs,
              float* __restrict__ out, int pass)
{
  __shared__ unsigned int ents[ECAP];
  __shared__ unsigned int h[BROWS], bs[BROWS], cur[BROWS];

  const int bkt = blockIdx.x, tid = threadIdx.x;
  const int bin = pass * NBKT + bkt;
  const unsigned int s = offs[(size_t)bin * NWGH];
  const unsigned int e = offs[(size_t)(bin + 1) * NWGH];
  int cnt = (int)(e - s); if (cnt > ECAP) cnt = ECAP;   // astronomically unlikely clamp

  if (tid < BROWS) h[tid] = 0u;
  __syncthreads();
  for (int i = tid; i < cnt; i += 512)
    atomicAdd(&h[sorted_g[s + i] >> 21], 1u);
  __syncthreads();
  // parallel exclusive scan of h -> bs (Kogge-Stone inclusive, then shift)
  if (tid < BROWS) bs[tid] = h[tid];
  __syncthreads();
#pragma unroll
  for (int o = 1; o < BROWS; o <<= 1) {
    unsigned int v = 0;
    if (tid < BROWS && tid >= o) v = bs[tid - o];
    __syncthreads();
    if (tid < BROWS) bs[tid] += v;
    __syncthreads();
  }
  if (tid < BROWS) {
    unsigned int ex = bs[tid] - h[tid];   // exclusive
    bs[tid] = ex;
    cur[tid] = ex;
  }
  __syncthreads();
  for (int i = tid; i < cnt; i += 512) {
    unsigned int en = sorted_g[s + i];
    unsigned int pos = atomicAdd(&cur[en >> 21], 1u);
    ents[pos] = (en & 0xFFE00000u) | (unsigned int)i;   // outl | rel-slot
  }
  __syncthreads();

  const int lane = tid & 63, wv = tid >> 6;            // 8 waves
  const int half = lane >> 5;                          // row parity within pair
  const int cl   = lane & 31;                          // channel pair (2cl, 2cl+1)
  const unsigned int pbase = (unsigned int)pass * (unsigned int)PASSC;
  const unsigned int segb = s - pbase;                 // pass-local segment base
  const unsigned int* pl = contrib + (size_t)cl * PASSC + segb;

#pragma unroll 1
  for (int rp = 0; rp < 8; ++rp) {                     // 8 iters x 2 rows = 16 rows/wave
    const int row  = wv * 16 + rp * 2 + half;
    const int grow = bkt * BROWS + row;
    const bool active = (grow < NROWS) && !(h[row] == 0u && pass);
    float ax = 0.f, ay = 0.f;
    if (active) {
      int j = (int)bs[row];
      const int je = j + (int)h[row];
      float bx = 0.f, by = 0.f, cx = 0.f, cy = 0.f, dx = 0.f, dy = 0.f;
      for (; j + 3 < je; j += 4) {                     // 4-way MLP unroll
        uint32_t w0 = pl[ents[j]     & 0x1FFFFFu];
        uint32_t w1 = pl[ents[j + 1] & 0x1FFFFFu];
        uint32_t w2 = pl[ents[j + 2] & 0x1FFFFFu];
        uint32_t w3 = pl[ents[j + 3] & 0x1FFFFFu];
        ax += bf2f(w0 & 0xFFFFu); ay += bf2f(w0 >> 16);
        bx += bf2f(w1 & 0xFFFFu); by += bf2f(w1 >> 16);
        cx += bf2f(w2 & 0xFFFFu); cy += bf2f(w2 >> 16);
        dx += bf2f(w3 & 0xFFFFu); dy += bf2f(w3 >> 16);
      }
      for (; j < je; ++j) {
        uint32_t w0 = pl[ents[j] & 0x1FFFFFu];
        ax += bf2f(w0 & 0xFFFFu); ay += bf2f(w0 >> 16);
      }
      ax += bx + cx + dx; ay += by + cy + dy;
      float* op = out + (size_t)grow * CDIM + cl * 2;
      if (pass) { float2 prev = *(const float2*)op; ax += prev.x; ay += prev.y; }
      float2 o2; o2.x = ax; o2.y = ay;
      *(float2*)op = o2;
    }
  }
}

extern "C" void kernel_launch(void* const* d_in, const int* in_sizes, int n_in,
                              void* d_out, int out_size, void* d_ws, size_t ws_size,
                              hipStream_t stream) {
  const float* in_feats = (const float*)d_in[0];
  const float* kernel   = (const float*)d_in[1];
  const int*   in_map   = (const int*)d_in[2];
  const int*   out_map  = (const int*)d_in[3];
  float* out = (float*)d_out;

  uint8_t* ws = (uint8_t*)d_ws;
  size_t off = 0;
  auto alloc = [&](size_t bytes) -> void* {
    void* p = ws + off;
    off += (bytes + 255) & ~(size_t)255;
    return p;
  };
  short* in_bf16         = (short*)alloc((size_t)NROWS * CDIM * 2);        // 25.6 MB
  short* wt_bf16         = (short*)alloc((size_t)KVOL * CDIM * CDIM * 2);  // 221 KB
  unsigned int* hist_g   = (unsigned int*)alloc((size_t)CELLS * 4);        // 4.05 MB
  unsigned int* offs     = (unsigned int*)alloc((size_t)(CELLS + 1) * 4);  // 4.05 MB
  unsigned int* bsum     = (unsigned int*)alloc(4096);
  unsigned int* sorted_g = (unsigned int*)alloc((size_t)TOTALC * 4);       // 16.2 MB
  unsigned int* inv      = (unsigned int*)alloc((size_t)TOTALC * 4);       // 16.2 MB
  unsigned int* contrib  = (unsigned int*)alloc((size_t)32 * PASSC * 4);   // 172.8 MB

  hipMemsetAsync(hist_g, 0, (size_t)CELLS * 4, stream);

  cvt_all<<<2048 + KVOL, 256, 0, stream>>>(in_feats, in_bf16, kernel, wt_bf16,
                                           NROWS * CDIM / 8);

  k_hist<<<NWGH, 256, 0, stream>>>(out_map, hist_g);

  const int sb = (CELLS + 1023) / 1024;   // 990 (< 1024: scan_bsum single-block OK)
  scan_local<<<sb, 1024, 0, stream>>>(hist_g, offs, bsum, CELLS);
  scan_bsum<<<1, 1024, 0, stream>>>(bsum, sb);
  scan_apply<<<sb, 1024, 0, stream>>>(offs, bsum, hist_g, CELLS);

  k_scatter<<<NWGH, 256, 0, stream>>>(out_map, offs, sorted_g, inv);

  for (int p = 0; p < NPASS; ++p) {
    dim3 g(227, KPP);   // 2043 blocks ~= 8/CU capacity
    k_gemm<<<g, 256, 0, stream>>>(in_bf16, wt_bf16, in_map, inv, contrib, p);
    k_reduce<<<NBKT, 512, 0, stream>>>(contrib, sorted_g, offs, out, p);
  }
}

// Round 18
// 513.305 us; speedup vs baseline: 6.0615x; 6.0615x over previous
//
#include <hip/hip_runtime.h>
#include <hip/hip_bf16.h>
#include <stdint.h>

// Problem constants
#define KVOL   27
#define MPAIRS 150000
#define NROWS  200000            // N_IN == N_OUT
#define CDIM   64
#define TOTALC (KVOL*MPAIRS)     // 4,050,000

// Pass / bucket geometry
#define NPASS  3
#define KPP    9                 // k-offsets per pass
#define PASSC  (KPP*MPAIRS)      // 1,350,000 (21 bits)
#define BROWS  128
#define NBKT   1563              // ceil(200000/128)
#define NPB    (NPASS*NBKT)      // 4689 (pass,bucket) bins
#define SUBW   8                 // sub-chunks per k for hist/scatter (divides 150000)
#define NWGH   (KVOL*SUBW)       // 216 WGs
#define CHUNKH (MPAIRS/SUBW)     // 18,750 exact
#define CELLS  (NPB*NWGH)        // 1,012,824 scan cells (sb=990 < 1024)
#define ECAP   1280              // per-(pass,bucket) entry capacity (mean 864, sd 29)

typedef __attribute__((ext_vector_type(8))) short bf16x8;
typedef __attribute__((ext_vector_type(4))) float f32x4;

__device__ __forceinline__ short f2bf(float f) {
  union { float f; uint32_t u; } v; v.f = f;
  uint32_t u = v.u;
  u += 0x7FFF + ((u >> 16) & 1);
  return (short)(u >> 16);
}
__device__ __forceinline__ float bf2f(uint32_t u16) {
  union { uint32_t u; float f; } v; v.u = u16 << 16; return v.f;
}

// ---- prologue: fused feats + weights convert (one launch) ----
__global__ void cvt_all(const float* __restrict__ in, short* __restrict__ out,
                        const float* __restrict__ w, short* __restrict__ wt, int n8) {
  if (blockIdx.x < KVOL) {                     // weight transpose blocks
    int k = blockIdx.x;
    const float* wk = w + (size_t)k * CDIM * CDIM;
    short* wtk = wt + (size_t)k * CDIM * CDIM;
    for (int t = threadIdx.x; t < CDIM * CDIM; t += blockDim.x) {
      int j = t >> 6, i = t & 63;
      wtk[j * CDIM + i] = f2bf(wk[i * CDIM + j]);
    }
    return;
  }
  int i = (blockIdx.x - KVOL) * blockDim.x + threadIdx.x;
  int stride = (gridDim.x - KVOL) * blockDim.x;
  for (; i < n8; i += stride) {
    const float* p = in + (size_t)i * 8;
    f32x4 f0 = *(const f32x4*)(p);
    f32x4 f1 = *(const f32x4*)(p + 4);
    bf16x8 o;
    o[0] = f2bf(f0[0]); o[1] = f2bf(f0[1]); o[2] = f2bf(f0[2]); o[3] = f2bf(f0[3]);
    o[4] = f2bf(f1[0]); o[5] = f2bf(f1[1]); o[6] = f2bf(f1[2]); o[7] = f2bf(f1[3]);
    *(bf16x8*)(out + (size_t)i * 8) = o;
  }
}

// ---- histogram: WG = (k, sub-chunk); LDS-private 1563 bucket bins ----
__global__ __launch_bounds__(256)
void k_hist(const int* __restrict__ om, unsigned int* __restrict__ hist_g) {
  __shared__ unsigned int h[NBKT];
  const int wg = blockIdx.x, tid = threadIdx.x;
  const int k = wg / SUBW, sub = wg - k * SUBW;
  const int pass = k / KPP;
  for (int i = tid; i < NBKT; i += 256) h[i] = 0u;
  __syncthreads();
  const int base = k * MPAIRS + sub * CHUNKH;
  for (int i = tid; i < CHUNKH; i += 256)
    atomicAdd(&h[((unsigned)om[base + i]) >> 7], 1u);
  __syncthreads();
  for (int b = tid; b < NBKT; b += 256)
    hist_g[(size_t)(pass * NBKT + b) * NWGH + wg] = h[b];
}

// ---- 3-kernel exclusive scan over CELLS ([bin][wg] cell-major) ----
__global__ void scan_local(const unsigned int* __restrict__ counts,
                           unsigned int* __restrict__ offsets,
                           unsigned int* __restrict__ bsum, int n) {
  __shared__ unsigned int sh[1024];
  int t = threadIdx.x;
  int idx = blockIdx.x * 1024 + t;
  unsigned int v = (idx < n) ? counts[idx] : 0u;
  sh[t] = v; __syncthreads();
  for (int o = 1; o < 1024; o <<= 1) {
    unsigned int u = (t >= o) ? sh[t - o] : 0u;
    __syncthreads();
    sh[t] += u;
    __syncthreads();
  }
  if (idx < n) offsets[idx] = sh[t] - v;
  if (t == 1023) bsum[blockIdx.x] = sh[1023];
}

__global__ void scan_bsum(unsigned int* __restrict__ bsum, int nb) {
  __shared__ unsigned int sh[1024];
  int t = threadIdx.x;
  unsigned int v = (t < nb) ? bsum[t] : 0u;
  sh[t] = v; __syncthreads();
  for (int o = 1; o < 1024; o <<= 1) {
    unsigned int u = (t >= o) ? sh[t - o] : 0u;
    __syncthreads();
    sh[t] += u;
    __syncthreads();
  }
  if (t < nb) bsum[t] = sh[t] - v;
}

__global__ void scan_apply(unsigned int* __restrict__ offsets,
                           const unsigned int* __restrict__ bsum,
                           const unsigned int* __restrict__ counts, int n) {
  int idx = blockIdx.x * 1024 + threadIdx.x;
  if (idx < n) {
    unsigned int o = offsets[idx] + bsum[blockIdx.x];
    offsets[idx] = o;
    if (idx == n - 1) offsets[n] = o + counts[idx];
  }
}

// ---- scatter 4B entries (outl<<21 | e_local) into (pass,bucket) slots ----
__global__ __launch_bounds__(256)
void k_scatter(const int* __restrict__ om,
               const unsigned int* __restrict__ offs, unsigned int* __restrict__ sorted_g) {
  __shared__ unsigned int cur[NBKT];
  const int wg = blockIdx.x, tid = threadIdx.x;
  const int k = wg / SUBW, sub = wg - k * SUBW;
  const int pass = k / KPP, kk = k - pass * KPP;
  for (int b = tid; b < NBKT; b += 256)
    cur[b] = offs[(size_t)(pass * NBKT + b) * NWGH + wg];
  __syncthreads();
  const int base = k * MPAIRS + sub * CHUNKH;
  const unsigned int elb = (unsigned)(kk * MPAIRS + sub * CHUNKH);
  for (int i = tid; i < CHUNKH; i += 256) {
    unsigned int o = (unsigned)om[base + i];
    unsigned int pos = atomicAdd(&cur[o >> 7], 1u);
    sorted_g[pos] = ((o & 127u) << 21) | (elb + (unsigned)i);
  }
}

// ---- GEMM (per pass): ORIGINAL k-major order, coalesced contrib writes,
// zero atomics. Swapped MFMA: lane (r,h) owns pair base+r, channels
// t*16+h*4+{0..3}. Single-tile loop (R12): cache-tuned, do NOT widen. ----
__global__ __launch_bounds__(256, 8)
void k_gemm(const short* __restrict__ a_bf16, const short* __restrict__ wt_bf16,
            const int* __restrict__ in_map, short* __restrict__ contrib, int pass)
{
  const int kk   = blockIdx.y;
  const int k    = pass * KPP + kk;
  const int lane = threadIdx.x & 63;
  const int wave = threadIdx.x >> 6;
  const int r    = lane & 15;
  const int h    = lane >> 4;

  bf16x8 b[4][2];
  const short* wtk = wt_bf16 + (size_t)k * CDIM * CDIM;
#pragma unroll
  for (int t = 0; t < 4; ++t)
#pragma unroll
    for (int c = 0; c < 2; ++c)
      b[t][c] = *(const bf16x8*)(wtk + (t * 16 + r) * CDIM + c * 32 + h * 8);

  const int* imk = in_map + (size_t)k * MPAIRS;
  const int ntiles = MPAIRS / 16;
  const int wstride = gridDim.x * 4;

  for (int tile = blockIdx.x * 4 + wave; tile < ntiles; tile += wstride) {
    const int base = tile * 16;
    const int in_row = imk[base + r];
    const short* arow = a_bf16 + (size_t)in_row * CDIM;
    bf16x8 a0 = *(const bf16x8*)(arow + h * 8);
    bf16x8 a1 = *(const bf16x8*)(arow + 32 + h * 8);

    f32x4 acc[4];
#pragma unroll
    for (int t = 0; t < 4; ++t) {
      acc[t] = (f32x4){0.f, 0.f, 0.f, 0.f};
      acc[t] = __builtin_amdgcn_mfma_f32_16x16x32_bf16(b[t][0], a0, acc[t], 0, 0, 0);
      acc[t] = __builtin_amdgcn_mfma_f32_16x16x32_bf16(b[t][1], a1, acc[t], 0, 0, 0);
    }

    short* crow = contrib + (size_t)(kk * MPAIRS + base + r) * CDIM;
#pragma unroll
    for (int t = 0; t < 4; ++t) {
      short4 s4;
      s4.x = f2bf(acc[t][0]); s4.y = f2bf(acc[t][1]);
      s4.z = f2bf(acc[t][2]); s4.w = f2bf(acc[t][3]);
      *(short4*)(crow + t * 16 + h * 4) = s4;
    }
  }
}

// ---- reduce (per pass): WG(512) per bucket; in-LDS row-sort (parallel scan);
// accumulate: QUARTER-wave per row (16 lanes x uint2 = 4 channels), 4 rows
// in flight per wave, 4/2/1 entry ladder -> 2x concurrent latency chains. ----
__global__ __launch_bounds__(512, 4)
void k_reduce(const short* __restrict__ contrib,
              const unsigned int* __restrict__ sorted_g,
              const unsigned int* __restrict__ offs,
              float* __restrict__ out, int pass)
{
  __shared__ unsigned int ents[ECAP];
  __shared__ unsigned int h[BROWS], bs[BROWS], cur[BROWS];

  const int bkt = blockIdx.x, tid = threadIdx.x;
  const int bin = pass * NBKT + bkt;
  const unsigned int s = offs[(size_t)bin * NWGH];
  const unsigned int e = offs[(size_t)(bin + 1) * NWGH];
  int cnt = (int)(e - s); if (cnt > ECAP) cnt = ECAP;   // astronomically unlikely clamp

  if (tid < BROWS) h[tid] = 0u;
  __syncthreads();
  for (int i = tid; i < cnt; i += 512)
    atomicAdd(&h[sorted_g[s + i] >> 21], 1u);
  __syncthreads();
  // parallel exclusive scan of h -> bs (Kogge-Stone inclusive, then shift)
  if (tid < BROWS) bs[tid] = h[tid];
  __syncthreads();
#pragma unroll
  for (int o = 1; o < BROWS; o <<= 1) {
    unsigned int v = 0;
    if (tid < BROWS && tid >= o) v = bs[tid - o];
    __syncthreads();
    if (tid < BROWS) bs[tid] += v;
    __syncthreads();
  }
  if (tid < BROWS) {
    unsigned int ex = bs[tid] - h[tid];   // exclusive
    bs[tid] = ex;
    cur[tid] = ex;
  }
  __syncthreads();
  for (int i = tid; i < cnt; i += 512) {
    unsigned int en = sorted_g[s + i];
    unsigned int pos = atomicAdd(&cur[en >> 21], 1u);
    ents[pos] = en;
  }
  __syncthreads();

  const int lane = tid & 63, wv = tid >> 6;            // 8 waves
  const int q    = lane >> 4;                          // row quarter 0..3
  const int cl4  = lane & 15;                          // channel quad (4 ch = uint2)
  const uint2* cb8 = (const uint2*)contrib;            // row = 16 x uint2

#pragma unroll 1
  for (int rp = 0; rp < 4; ++rp) {                     // 4 iters x 4 rows = 16 rows/wave
    const int row  = wv * 16 + rp * 4 + q;
    const int grow = bkt * BROWS + row;
    const bool active = (grow < NROWS) && !(h[row] == 0u && pass);
    if (active) {
      float a0 = 0.f, a1 = 0.f, a2 = 0.f, a3 = 0.f;
      float b0 = 0.f, b1 = 0.f, b2 = 0.f, b3 = 0.f;
      int j = (int)bs[row];
      const int je = j + (int)h[row];
      for (; j + 3 < je; j += 4) {                     // 4-deep
        uint2 w0 = cb8[(size_t)(ents[j]     & 0x1FFFFFu) * 16 + cl4];
        uint2 w1 = cb8[(size_t)(ents[j + 1] & 0x1FFFFFu) * 16 + cl4];
        uint2 w2 = cb8[(size_t)(ents[j + 2] & 0x1FFFFFu) * 16 + cl4];
        uint2 w3 = cb8[(size_t)(ents[j + 3] & 0x1FFFFFu) * 16 + cl4];
        a0 += bf2f(w0.x & 0xFFFFu); a1 += bf2f(w0.x >> 16);
        a2 += bf2f(w0.y & 0xFFFFu); a3 += bf2f(w0.y >> 16);
        b0 += bf2f(w1.x & 0xFFFFu); b1 += bf2f(w1.x >> 16);
        b2 += bf2f(w1.y & 0xFFFFu); b3 += bf2f(w1.y >> 16);
        a0 += bf2f(w2.x & 0xFFFFu); a1 += bf2f(w2.x >> 16);
        a2 += bf2f(w2.y & 0xFFFFu); a3 += bf2f(w2.y >> 16);
        b0 += bf2f(w3.x & 0xFFFFu); b1 += bf2f(w3.x >> 16);
        b2 += bf2f(w3.y & 0xFFFFu); b3 += bf2f(w3.y >> 16);
      }
      if (j + 1 < je) {                                // 2-deep tail
        uint2 w0 = cb8[(size_t)(ents[j]     & 0x1FFFFFu) * 16 + cl4];
        uint2 w1 = cb8[(size_t)(ents[j + 1] & 0x1FFFFFu) * 16 + cl4];
        a0 += bf2f(w0.x & 0xFFFFu); a1 += bf2f(w0.x >> 16);
        a2 += bf2f(w0.y & 0xFFFFu); a3 += bf2f(w0.y >> 16);
        b0 += bf2f(w1.x & 0xFFFFu); b1 += bf2f(w1.x >> 16);
        b2 += bf2f(w1.y & 0xFFFFu); b3 += bf2f(w1.y >> 16);
        j += 2;
      }
      if (j < je) {                                    // 1 tail
        uint2 w0 = cb8[(size_t)(ents[j] & 0x1FFFFFu) * 16 + cl4];
        a0 += bf2f(w0.x & 0xFFFFu); a1 += bf2f(w0.x >> 16);
        a2 += bf2f(w0.y & 0xFFFFu); a3 += bf2f(w0.y >> 16);
      }
      a0 += b0; a1 += b1; a2 += b2; a3 += b3;
      float* op = out + (size_t)grow * CDIM + cl4 * 4;
      if (pass) {
        float4 prev = *(const float4*)op;
        a0 += prev.x; a1 += prev.y; a2 += prev.z; a3 += prev.w;
      }
      float4 o4; o4.x = a0; o4.y = a1; o4.z = a2; o4.w = a3;
      *(float4*)op = o4;
    }
  }
}

extern "C" void kernel_launch(void* const* d_in, const int* in_sizes, int n_in,
                              void* d_out, int out_size, void* d_ws, size_t ws_size,
                              hipStream_t stream) {
  const float* in_feats = (const float*)d_in[0];
  const float* kernel   = (const float*)d_in[1];
  const int*   in_map   = (const int*)d_in[2];
  const int*   out_map  = (const int*)d_in[3];
  float* out = (float*)d_out;

  uint8_t* ws = (uint8_t*)d_ws;
  size_t off = 0;
  auto alloc = [&](size_t bytes) -> void* {
    void* p = ws + off;
    off += (bytes + 255) & ~(size_t)255;
    return p;
  };
  short* in_bf16         = (short*)alloc((size_t)NROWS * CDIM * 2);        // 25.6 MB
  short* wt_bf16         = (short*)alloc((size_t)KVOL * CDIM * CDIM * 2);  // 221 KB
  unsigned int* hist_g   = (unsigned int*)alloc((size_t)CELLS * 4);        // 4.05 MB
  unsigned int* offs     = (unsigned int*)alloc((size_t)(CELLS + 1) * 4);  // 4.05 MB
  unsigned int* bsum     = (unsigned int*)alloc(4096);
  unsigned int* sorted_g = (unsigned int*)alloc((size_t)TOTALC * 4);       // 16.2 MB
  short* contrib         = (short*)alloc((size_t)PASSC * CDIM * 2);        // 172.8 MB

  hipMemsetAsync(hist_g, 0, (size_t)CELLS * 4, stream);

  cvt_all<<<2048 + KVOL, 256, 0, stream>>>(in_feats, in_bf16, kernel, wt_bf16,
                                           NROWS * CDIM / 8);

  k_hist<<<NWGH, 256, 0, stream>>>(out_map, hist_g);

  const int sb = (CELLS + 1023) / 1024;   // 990 (< 1024: scan_bsum single-block OK)
  scan_local<<<sb, 1024, 0, stream>>>(hist_g, offs, bsum, CELLS);
  scan_bsum<<<1, 1024, 0, stream>>>(bsum, sb);
  scan_apply<<<sb, 1024, 0, stream>>>(offs, bsum, hist_g, CELLS);

  k_scatter<<<NWGH, 256, 0, stream>>>(out_map, offs, sorted_g);

  for (int p = 0; p < NPASS; ++p) {
    dim3 g(227, KPP);   // 2043 blocks ~= 8/CU capacity
    k_gemm<<<g, 256, 0, stream>>>(in_bf16, wt_bf16, in_map, contrib, p);
    k_reduce<<<NBKT, 512, 0, stream>>>(contrib, sorted_g, offs, out, p);
  }
}

// Round 19
// 488.938 us; speedup vs baseline: 6.3636x; 1.0498x over previous
//
#include <hip/hip_runtime.h>
#include <hip/hip_bf16.h>
#include <stdint.h>

// Problem constants
#define KVOL   27
#define MPAIRS 150000
#define NROWS  200000            // N_IN == N_OUT
#define CDIM   64
#define TOTALC (KVOL*MPAIRS)     // 4,050,000

// Pass / bucket geometry
#define NPASS  3
#define KPP    9                 // k-offsets per pass
#define PASSC  (KPP*MPAIRS)      // 1,350,000 (21 bits)
#define BROWS  128
#define NBKT   1563              // ceil(200000/128)
#define NPB    (NPASS*NBKT)      // 4689 (pass,bucket) bins
#define SUBW   8                 // sub-chunks per k for hist/scatter (divides 150000)
#define NWGH   (KVOL*SUBW)       // 216 WGs
#define CHUNKH (MPAIRS/SUBW)     // 18,750 exact
#define CELLS  (NPB*NWGH)        // 1,012,824 scan cells (sb=990 < 1024)
#define ECAP   1280              // per-(pass,bucket) entry capacity (mean 864, sd 29)

typedef __attribute__((ext_vector_type(8))) short bf16x8;
typedef __attribute__((ext_vector_type(4))) float f32x4;

__device__ __forceinline__ unsigned short f2bfu(float f) {
  union { float f; uint32_t u; } v; v.f = f;
  uint32_t u = v.u;
  u += 0x7FFF + ((u >> 16) & 1);
  return (unsigned short)(u >> 16);
}
__device__ __forceinline__ short f2bf(float f) { return (short)f2bfu(f); }
__device__ __forceinline__ float bf2f(uint32_t u16) {
  union { uint32_t u; float f; } v; v.u = u16 << 16; return v.f;
}

// ---- prologue: fused feats + weights convert (one launch) ----
__global__ void cvt_all(const float* __restrict__ in, short* __restrict__ out,
                        const float* __restrict__ w, short* __restrict__ wt, int n8) {
  if (blockIdx.x < KVOL) {                     // weight transpose blocks
    int k = blockIdx.x;
    const float* wk = w + (size_t)k * CDIM * CDIM;
    short* wtk = wt + (size_t)k * CDIM * CDIM;
    for (int t = threadIdx.x; t < CDIM * CDIM; t += blockDim.x) {
      int j = t >> 6, i = t & 63;
      wtk[j * CDIM + i] = f2bf(wk[i * CDIM + j]);
    }
    return;
  }
  int i = (blockIdx.x - KVOL) * blockDim.x + threadIdx.x;
  int stride = (gridDim.x - KVOL) * blockDim.x;
  for (; i < n8; i += stride) {
    const float* p = in + (size_t)i * 8;
    f32x4 f0 = *(const f32x4*)(p);
    f32x4 f1 = *(const f32x4*)(p + 4);
    bf16x8 o;
    o[0] = f2bf(f0[0]); o[1] = f2bf(f0[1]); o[2] = f2bf(f0[2]); o[3] = f2bf(f0[3]);
    o[4] = f2bf(f1[0]); o[5] = f2bf(f1[1]); o[6] = f2bf(f1[2]); o[7] = f2bf(f1[3]);
    *(bf16x8*)(out + (size_t)i * 8) = o;
  }
}

// ---- histogram: WG = (k, sub-chunk); LDS-private 1563 bucket bins ----
__global__ __launch_bounds__(256)
void k_hist(const int* __restrict__ om, unsigned int* __restrict__ hist_g) {
  __shared__ unsigned int h[NBKT];
  const int wg = blockIdx.x, tid = threadIdx.x;
  const int k = wg / SUBW, sub = wg - k * SUBW;
  const int pass = k / KPP;
  for (int i = tid; i < NBKT; i += 256) h[i] = 0u;
  __syncthreads();
  const int base = k * MPAIRS + sub * CHUNKH;
  for (int i = tid; i < CHUNKH; i += 256)
    atomicAdd(&h[((unsigned)om[base + i]) >> 7], 1u);
  __syncthreads();
  for (int b = tid; b < NBKT; b += 256)
    hist_g[(size_t)(pass * NBKT + b) * NWGH + wg] = h[b];
}

// ---- 3-kernel exclusive scan over CELLS ([bin][wg] cell-major) ----
__global__ void scan_local(const unsigned int* __restrict__ counts,
                           unsigned int* __restrict__ offsets,
                           unsigned int* __restrict__ bsum, int n) {
  __shared__ unsigned int sh[1024];
  int t = threadIdx.x;
  int idx = blockIdx.x * 1024 + t;
  unsigned int v = (idx < n) ? counts[idx] : 0u;
  sh[t] = v; __syncthreads();
  for (int o = 1; o < 1024; o <<= 1) {
    unsigned int u = (t >= o) ? sh[t - o] : 0u;
    __syncthreads();
    sh[t] += u;
    __syncthreads();
  }
  if (idx < n) offsets[idx] = sh[t] - v;
  if (t == 1023) bsum[blockIdx.x] = sh[1023];
}

__global__ void scan_bsum(unsigned int* __restrict__ bsum, int nb) {
  __shared__ unsigned int sh[1024];
  int t = threadIdx.x;
  unsigned int v = (t < nb) ? bsum[t] : 0u;
  sh[t] = v; __syncthreads();
  for (int o = 1; o < 1024; o <<= 1) {
    unsigned int u = (t >= o) ? sh[t - o] : 0u;
    __syncthreads();
    sh[t] += u;
    __syncthreads();
  }
  if (t < nb) bsum[t] = sh[t] - v;
}

__global__ void scan_apply(unsigned int* __restrict__ offsets,
                           const unsigned int* __restrict__ bsum,
                           const unsigned int* __restrict__ counts, int n) {
  int idx = blockIdx.x * 1024 + threadIdx.x;
  if (idx < n) {
    unsigned int o = offsets[idx] + bsum[blockIdx.x];
    offsets[idx] = o;
    if (idx == n - 1) offsets[n] = o + counts[idx];
  }
}

// ---- scatter 4B entries (outl<<21 | e_local) into (pass,bucket) slots ----
__global__ __launch_bounds__(256)
void k_scatter(const int* __restrict__ om,
               const unsigned int* __restrict__ offs, unsigned int* __restrict__ sorted_g) {
  __shared__ unsigned int cur[NBKT];
  const int wg = blockIdx.x, tid = threadIdx.x;
  const int k = wg / SUBW, sub = wg - k * SUBW;
  const int pass = k / KPP, kk = k - pass * KPP;
  for (int b = tid; b < NBKT; b += 256)
    cur[b] = offs[(size_t)(pass * NBKT + b) * NWGH + wg];
  __syncthreads();
  const int base = k * MPAIRS + sub * CHUNKH;
  const unsigned int elb = (unsigned)(kk * MPAIRS + sub * CHUNKH);
  for (int i = tid; i < CHUNKH; i += 256) {
    unsigned int o = (unsigned)om[base + i];
    unsigned int pos = atomicAdd(&cur[o >> 7], 1u);
    sorted_g[pos] = ((o & 127u) << 21) | (elb + (unsigned)i);
  }
}

// ---- GEMM (per pass): ORIGINAL k-major order, zero atomics. Swapped MFMA:
// lane (r,h) owns pair base+r, channels t*16+h*4+{0..3}. Contrib stores are
// NONTEMPORAL (8B packed): the 169MB/pass write stream must not evict the
// 25.6MB gather table from L3 (R18 FETCH showed 3x re-fetch churn). ----
__global__ __launch_bounds__(256, 8)
void k_gemm(const short* __restrict__ a_bf16, const short* __restrict__ wt_bf16,
            const int* __restrict__ in_map, short* __restrict__ contrib, int pass)
{
  const int kk   = blockIdx.y;
  const int k    = pass * KPP + kk;
  const int lane = threadIdx.x & 63;
  const int wave = threadIdx.x >> 6;
  const int r    = lane & 15;
  const int h    = lane >> 4;

  bf16x8 b[4][2];
  const short* wtk = wt_bf16 + (size_t)k * CDIM * CDIM;
#pragma unroll
  for (int t = 0; t < 4; ++t)
#pragma unroll
    for (int c = 0; c < 2; ++c)
      b[t][c] = *(const bf16x8*)(wtk + (t * 16 + r) * CDIM + c * 32 + h * 8);

  const int* imk = in_map + (size_t)k * MPAIRS;
  const int ntiles = MPAIRS / 16;
  const int wstride = gridDim.x * 4;

  for (int tile = blockIdx.x * 4 + wave; tile < ntiles; tile += wstride) {
    const int base = tile * 16;
    const int in_row = imk[base + r];
    const short* arow = a_bf16 + (size_t)in_row * CDIM;
    bf16x8 a0 = *(const bf16x8*)(arow + h * 8);
    bf16x8 a1 = *(const bf16x8*)(arow + 32 + h * 8);

    f32x4 acc[4];
#pragma unroll
    for (int t = 0; t < 4; ++t) {
      acc[t] = (f32x4){0.f, 0.f, 0.f, 0.f};
      acc[t] = __builtin_amdgcn_mfma_f32_16x16x32_bf16(b[t][0], a0, acc[t], 0, 0, 0);
      acc[t] = __builtin_amdgcn_mfma_f32_16x16x32_bf16(b[t][1], a1, acc[t], 0, 0, 0);
    }

    short* crow = contrib + (size_t)(kk * MPAIRS + base + r) * CDIM;
#pragma unroll
    for (int t = 0; t < 4; ++t) {
      unsigned long long pk =
          (unsigned long long)f2bfu(acc[t][0])
        | ((unsigned long long)f2bfu(acc[t][1]) << 16)
        | ((unsigned long long)f2bfu(acc[t][2]) << 32)
        | ((unsigned long long)f2bfu(acc[t][3]) << 48);
      __builtin_nontemporal_store(pk, (unsigned long long*)(crow + t * 16 + h * 4));
    }
  }
}

// ---- reduce (per pass): WG(512) per bucket; in-LDS row-sort (parallel scan);
// accumulate: QUARTER-wave per row (16 lanes x 8B = 4 channels), 4 rows in
// flight per wave, 4/2/1 ladder. Contrib loads NONTEMPORAL (read-once). ----
__global__ __launch_bounds__(512, 4)
void k_reduce(const short* __restrict__ contrib,
              const unsigned int* __restrict__ sorted_g,
              const unsigned int* __restrict__ offs,
              float* __restrict__ out, int pass)
{
  __shared__ unsigned int ents[ECAP];
  __shared__ unsigned int h[BROWS], bs[BROWS], cur[BROWS];

  const int bkt = blockIdx.x, tid = threadIdx.x;
  const int bin = pass * NBKT + bkt;
  const unsigned int s = offs[(size_t)bin * NWGH];
  const unsigned int e = offs[(size_t)(bin + 1) * NWGH];
  int cnt = (int)(e - s); if (cnt > ECAP) cnt = ECAP;   // astronomically unlikely clamp

  if (tid < BROWS) h[tid] = 0u;
  __syncthreads();
  for (int i = tid; i < cnt; i += 512)
    atomicAdd(&h[sorted_g[s + i] >> 21], 1u);
  __syncthreads();
  // parallel exclusive scan of h -> bs (Kogge-Stone inclusive, then shift)
  if (tid < BROWS) bs[tid] = h[tid];
  __syncthreads();
#pragma unroll
  for (int o = 1; o < BROWS; o <<= 1) {
    unsigned int v = 0;
    if (tid < BROWS && tid >= o) v = bs[tid - o];
    __syncthreads();
    if (tid < BROWS) bs[tid] += v;
    __syncthreads();
  }
  if (tid < BROWS) {
    unsigned int ex = bs[tid] - h[tid];   // exclusive
    bs[tid] = ex;
    cur[tid] = ex;
  }
  __syncthreads();
  for (int i = tid; i < cnt; i += 512) {
    unsigned int en = sorted_g[s + i];
    unsigned int pos = atomicAdd(&cur[en >> 21], 1u);
    ents[pos] = en;
  }
  __syncthreads();

  const int lane = tid & 63, wv = tid >> 6;            // 8 waves
  const int q    = lane >> 4;                          // row quarter 0..3
  const int cl4  = lane & 15;                          // channel quad (4 ch = 8B)
  const unsigned long long* cb = (const unsigned long long*)contrib;  // row = 16 x 8B

#pragma unroll 1
  for (int rp = 0; rp < 4; ++rp) {                     // 4 iters x 4 rows = 16 rows/wave
    const int row  = wv * 16 + rp * 4 + q;
    const int grow = bkt * BROWS + row;
    const bool active = (grow < NROWS) && !(h[row] == 0u && pass);
    if (active) {
      float a0 = 0.f, a1 = 0.f, a2 = 0.f, a3 = 0.f;
      float b0 = 0.f, b1 = 0.f, b2 = 0.f, b3 = 0.f;
      int j = (int)bs[row];
      const int je = j + (int)h[row];
      for (; j + 3 < je; j += 4) {                     // 4-deep
        unsigned long long w0 = __builtin_nontemporal_load(&cb[(size_t)(ents[j]     & 0x1FFFFFu) * 16 + cl4]);
        unsigned long long w1 = __builtin_nontemporal_load(&cb[(size_t)(ents[j + 1] & 0x1FFFFFu) * 16 + cl4]);
        unsigned long long w2 = __builtin_nontemporal_load(&cb[(size_t)(ents[j + 2] & 0x1FFFFFu) * 16 + cl4]);
        unsigned long long w3 = __builtin_nontemporal_load(&cb[(size_t)(ents[j + 3] & 0x1FFFFFu) * 16 + cl4]);
        a0 += bf2f((uint32_t)w0 & 0xFFFFu); a1 += bf2f(((uint32_t)w0) >> 16);
        a2 += bf2f((uint32_t)(w0 >> 32) & 0xFFFFu); a3 += bf2f((uint32_t)(w0 >> 48));
        b0 += bf2f((uint32_t)w1 & 0xFFFFu); b1 += bf2f(((uint32_t)w1) >> 16);
        b2 += bf2f((uint32_t)(w1 >> 32) & 0xFFFFu); b3 += bf2f((uint32_t)(w1 >> 48));
        a0 += bf2f((uint32_t)w2 & 0xFFFFu); a1 += bf2f(((uint32_t)w2) >> 16);
        a2 += bf2f((uint32_t)(w2 >> 32) & 0xFFFFu); a3 += bf2f((uint32_t)(w2 >> 48));
        b0 += bf2f((uint32_t)w3 & 0xFFFFu); b1 += bf2f(((uint32_t)w3) >> 16);
        b2 += bf2f((uint32_t)(w3 >> 32) & 0xFFFFu); b3 += bf2f((uint32_t)(w3 >> 48));
      }
      if (j + 1 < je) {                                // 2-deep tail
        unsigned long long w0 = __builtin_nontemporal_load(&cb[(size_t)(ents[j]     & 0x1FFFFFu) * 16 + cl4]);
        unsigned long long w1 = __builtin_nontemporal_load(&cb[(size_t)(ents[j + 1] & 0x1FFFFFu) * 16 + cl4]);
        a0 += bf2f((uint32_t)w0 & 0xFFFFu); a1 += bf2f(((uint32_t)w0) >> 16);
        a2 += bf2f((uint32_t)(w0 >> 32) & 0xFFFFu); a3 += bf2f((uint32_t)(w0 >> 48));
        b0 += bf2f((uint32_t)w1 & 0xFFFFu); b1 += bf2f(((uint32_t)w1) >> 16);
        b2 += bf2f((uint32_t)(w1 >> 32) & 0xFFFFu); b3 += bf2f((uint32_t)(w1 >> 48));
        j += 2;
      }
      if (j < je) {                                    // 1 tail
        unsigned long long w0 = __builtin_nontemporal_load(&cb[(size_t)(ents[j] & 0x1FFFFFu) * 16 + cl4]);
        a0 += bf2f((uint32_t)w0 & 0xFFFFu); a1 += bf2f(((uint32_t)w0) >> 16);
        a2 += bf2f((uint32_t)(w0 >> 32) & 0xFFFFu); a3 += bf2f((uint32_t)(w0 >> 48));
      }
      a0 += b0; a1 += b1; a2 += b2; a3 += b3;
      float* op = out + (size_t)grow * CDIM + cl4 * 4;
      if (pass) {
        float4 prev = *(const float4*)op;
        a0 += prev.x; a1 += prev.y; a2 += prev.z; a3 += prev.w;
      }
      float4 o4; o4.x = a0; o4.y = a1; o4.z = a2; o4.w = a3;
      *(float4*)op = o4;
    }
  }
}

extern "C" void kernel_launch(void* const* d_in, const int* in_sizes, int n_in,
                              void* d_out, int out_size, void* d_ws, size_t ws_size,
                              hipStream_t stream) {
  const float* in_feats = (const float*)d_in[0];
  const float* kernel   = (const float*)d_in[1];
  const int*   in_map   = (const int*)d_in[2];
  const int*   out_map  = (const int*)d_in[3];
  float* out = (float*)d_out;

  uint8_t* ws = (uint8_t*)d_ws;
  size_t off = 0;
  auto alloc = [&](size_t bytes) -> void* {
    void* p = ws + off;
    off += (bytes + 255) & ~(size_t)255;
    return p;
  };
  short* in_bf16         = (short*)alloc((size_t)NROWS * CDIM * 2);        // 25.6 MB
  short* wt_bf16         = (short*)alloc((size_t)KVOL * CDIM * CDIM * 2);  // 221 KB
  unsigned int* hist_g   = (unsigned int*)alloc((size_t)CELLS * 4);        // 4.05 MB
  unsigned int* offs     = (unsigned int*)alloc((size_t)(CELLS + 1) * 4);  // 4.05 MB
  unsigned int* bsum     = (unsigned int*)alloc(4096);
  unsigned int* sorted_g = (unsigned int*)alloc((size_t)TOTALC * 4);       // 16.2 MB
  short* contrib         = (short*)alloc((size_t)PASSC * CDIM * 2);        // 172.8 MB

  hipMemsetAsync(hist_g, 0, (size_t)CELLS * 4, stream);

  cvt_all<<<2048 + KVOL, 256, 0, stream>>>(in_feats, in_bf16, kernel, wt_bf16,
                                           NROWS * CDIM / 8);

  k_hist<<<NWGH, 256, 0, stream>>>(out_map, hist_g);

  const int sb = (CELLS + 1023) / 1024;   // 990 (< 1024: scan_bsum single-block OK)
  scan_local<<<sb, 1024, 0, stream>>>(hist_g, offs, bsum, CELLS);
  scan_bsum<<<1, 1024, 0, stream>>>(bsum, sb);
  scan_apply<<<sb, 1024, 0, stream>>>(offs, bsum, hist_g, CELLS);

  k_scatter<<<NWGH, 256, 0, stream>>>(out_map, offs, sorted_g);

  for (int p = 0; p < NPASS; ++p) {
    dim3 g(227, KPP);   // 2043 blocks ~= 8/CU capacity
    k_gemm<<<g, 256, 0, stream>>>(in_bf16, wt_bf16, in_map, contrib, p);
    k_reduce<<<NBKT, 512, 0, stream>>>(contrib, sorted_g, offs, out, p);
  }
}